// Round 3
// baseline (603.548 us; speedup 1.0000x reference)
//
#include <hip/hip_runtime.h>
#include <hip/hip_bf16.h>

// FlowNetC correlation on MI355X (gfx950).
// out[b, dyi*21+dxi, y, x] = (1/256) * sum_c in1[b,c,y,x] * in2pad[b,c, y+2dyi-20, x+2dxi-20]
//
// Strategy: per (b, y, dyi) this is a 21-diagonal band of A1^T * A2 where
//   A1 = in1 row (C=256 x 128), A2 = zero-padded in2 row (C=256 x 168).
// Split x by parity (displacement stride 2 preserves parity): per parity p,
//   C[m, k] = sum_c A1p[c, m] * A2p[c, k],  m in [0,64), k = m + dxi in [0,84).
// Computed with mfma_f32_16x16x32_bf16 tiles (4 m-tiles x 3 band n-tiles).
//
// Pre-passes convert f32 NCHW -> bf16 [b][y][p][row][c] with:
//  - zero padding baked into in2t rows (k in [10,74) valid),
//  - XOR swizzle of 16B c-blocks (blk ^= row&7) baked into the GLOBAL layout
//    so correlation stages with linear global_load_lds (16B) and reads
//    fragments bank-spread (both-sides-or-neither rule).
//
// Defensive: if ws_size < 120 MB the main path's workspace writes would be
// OOB (container-killing). In that case use a workspace-free f32 fallback.

typedef short short8 __attribute__((ext_vector_type(8)));
typedef float f32x4 __attribute__((ext_vector_type(4)));

// sizes
// in1t: [8][96][2][64][256] bf16 = 50331648 B
// in2t: [8][96][2][96][256] bf16 = 75497472 B
#define IN1T_BYTES 50331648ull
#define WS_NEEDED 125829120ull

__device__ __forceinline__ unsigned short f2bf(float f) {
  union { float f; unsigned int u; } v; v.f = f;
  unsigned int u = v.u;
  u += 0x7fffu + ((u >> 16) & 1u);   // round-to-nearest-even
  return (unsigned short)(u >> 16);
}

__device__ __forceinline__ void gload16(const unsigned short* g, unsigned short* l) {
  __builtin_amdgcn_global_load_lds((__attribute__((address_space(1))) unsigned int*)g,
                                   (__attribute__((address_space(3))) unsigned int*)l,
                                   16, 0, 0);
}

// ---------------- pre-pass: in1 -> in1t [b][y][p][m 64][c 256] ----------------
__global__ __launch_bounds__(256) void t1_kernel(const float* __restrict__ in1,
                                                 unsigned short* __restrict__ in1t) {
  __shared__ float sm[64][129];
  int bid = blockIdx.x;            // 8*96*4
  int cchunk = bid & 3;
  int t = bid >> 2;
  int y = t % 96;
  int b = t / 96;
  int c0 = cchunk * 64;
  for (int i = threadIdx.x; i < 64 * 128; i += 256) {
    int cl = i >> 7, x = i & 127;
    sm[cl][x] = in1[(((size_t)(b * 256 + c0 + cl)) * 96 + y) * 128 + x];
  }
  __syncthreads();
  size_t obase = ((size_t)(b * 96 + y)) * (2 * 64 * 256);
  for (int u = threadIdx.x; u < 1024; u += 256) {
    int p = u >> 9, m = (u >> 3) & 63, cb = u & 7;
    int x = p + 2 * m;
    short8 w;
#pragma unroll
    for (int e = 0; e < 8; ++e) w[e] = (short)f2bf(sm[cb * 8 + e][x]);
    size_t o = obase + ((size_t)(p * 64 + m)) * 256 + c0 + ((cb ^ (m & 7)) << 3);
    *reinterpret_cast<short8*>(in1t + o) = w;
  }
}

// ---------------- pre-pass: in2 -> in2t [b][y2][p][k 96][c 256] ----------------
// value(p,k) = in2[b,c,y2, p+2k-20] if in-range else 0
__global__ __launch_bounds__(256) void t2_kernel(const float* __restrict__ in2,
                                                 unsigned short* __restrict__ in2t) {
  __shared__ float sm[64][129];
  int bid = blockIdx.x;            // 8*96*4
  int cchunk = bid & 3;
  int t = bid >> 2;
  int y2 = t % 96;
  int b = t / 96;
  int c0 = cchunk * 64;
  for (int i = threadIdx.x; i < 64 * 128; i += 256) {
    int cl = i >> 7, x = i & 127;
    sm[cl][x] = in2[(((size_t)(b * 256 + c0 + cl)) * 96 + y2) * 128 + x];
  }
  __syncthreads();
  size_t obase = ((size_t)(b * 96 + y2)) * (2 * 96 * 256);
  for (int u = threadIdx.x; u < 1536; u += 256) {
    int p = u / 768;
    int r = u % 768;
    int k = r >> 3, cb = r & 7;
    int x2 = p + 2 * k - 20;
    bool ok = (unsigned)x2 < 128u;
    short8 w;
#pragma unroll
    for (int e = 0; e < 8; ++e) w[e] = ok ? (short)f2bf(sm[cb * 8 + e][x2]) : (short)0;
    size_t o = obase + ((size_t)(p * 96 + k)) * 256 + c0 + ((cb ^ (k & 7)) << 3);
    *reinterpret_cast<short8*>(in2t + o) = w;
  }
}

// ---------------- correlation kernel ----------------
// block = (b, y, dyi); 256 threads = 4 waves = (parity p, k-split cs)
// LDS: A 2buf x [128 rows(2p x 64m)] x 64c bf16 = 32 KB
//      B 2buf x [192 rows(2p x 96k)] x 64c bf16 = 48 KB   -> 80 KB, 2 blocks/CU
__global__ __launch_bounds__(256) void corr_kernel(const unsigned short* __restrict__ in1t,
                                                   const unsigned short* __restrict__ in2t,
                                                   float* __restrict__ out) {
  __shared__ unsigned short ldsA[2][128][64];
  __shared__ unsigned short ldsB[2][192][64];

  int bid = blockIdx.x;                       // 16128 = 8*96*21
  int wg = (bid & 7) * 2016 + (bid >> 3);     // bijective XCD swizzle (16128 % 8 == 0)
  int b = wg / 2016;
  int r0 = wg % 2016;
  int y = r0 / 21;
  int dyi = r0 % 21;
  int y2 = y + 2 * dyi - 20;
  int tid = threadIdx.x;

  if ((unsigned)y2 >= 96u) {                  // fully-padded rows -> zero output
    f32x4 z = {0.f, 0.f, 0.f, 0.f};
    for (int i = tid; i < 672; i += 256) {
      int oxi = i >> 5, xq = i & 31;
      size_t o = (((size_t)(b * 441 + dyi * 21 + oxi)) * 96 + y) * 128 + xq * 4;
      *reinterpret_cast<f32x4*>(out + o) = z;
    }
    return;
  }

  int lane = tid & 63;
  int wid = tid >> 6;
  int p = wid & 1, cs = wid >> 1;

  size_t baseA = ((size_t)(b * 96 + y)) * 32768;    // 2*64*256
  size_t baseB = ((size_t)(b * 96 + y2)) * 49152;   // 2*96*256

  int i8 = lane >> 3, seg = lane & 7;

  auto stage = [&](int buf, int n) {
    int c0 = n * 64;
    for (int t = wid; t < 40; t += 4) {
      if (t < 16) {  // A: 16 instrs x (8 rows x 128 B)
        const unsigned short* g = in1t + baseA + (size_t)(t * 8 + i8) * 256 + c0 + seg * 8;
        unsigned short* l = &ldsA[buf][0][0] + t * 512 + lane * 8;
        gload16(g, l);
      } else {       // B: 24 instrs
        int j = t - 16;
        const unsigned short* g = in2t + baseB + (size_t)(j * 8 + i8) * 256 + c0 + seg * 8;
        unsigned short* l = &ldsB[buf][0][0] + j * 512 + lane * 8;
        gload16(g, l);
      }
    }
  };

  f32x4 acc[12];
#pragma unroll
  for (int t = 0; t < 12; ++t) acc[t] = (f32x4){0.f, 0.f, 0.f, 0.f};

  int ml = lane & 15, g4 = lane >> 4, q = lane & 7;
  int blk8 = ((cs * 4 + g4) ^ q) * 8;   // swizzled 16B-block, matches pre-pass (row&7 == lane&7)

  stage(0, 0);
  __syncthreads();

  for (int n = 0; n < 4; ++n) {
    if (n < 3) stage((n + 1) & 1, n + 1);
    int buf = n & 1;
    const unsigned short* lA = &ldsA[buf][p * 64][0];
    const unsigned short* lB = &ldsB[buf][p * 96][0];
    short8 af[4], bfr[6];
#pragma unroll
    for (int mt = 0; mt < 4; ++mt)
      af[mt] = *reinterpret_cast<const short8*>(lA + (16 * mt + ml) * 64 + blk8);
#pragma unroll
    for (int nt = 0; nt < 6; ++nt)
      bfr[nt] = *reinterpret_cast<const short8*>(lB + (16 * nt + ml) * 64 + blk8);
#pragma unroll
    for (int mt = 0; mt < 4; ++mt)
#pragma unroll
      for (int jj = 0; jj < 3; ++jj)
        acc[mt * 3 + jj] = __builtin_amdgcn_mfma_f32_16x16x32_bf16(
            af[mt], bfr[mt + jj], acc[mt * 3 + jj], 0, 0, 0);
    __syncthreads();
  }

  // epilogue: band-extract into LDS [21][128] f32, then coalesced stores.
  float(*eb)[128] = reinterpret_cast<float(*)[128]>(&ldsA[0][0][0]);
  const float sc = 1.0f / 256.0f;
  if (cs == 0) {
#pragma unroll
    for (int mt = 0; mt < 4; ++mt)
#pragma unroll
      for (int jj = 0; jj < 3; ++jj)
#pragma unroll
        for (int r = 0; r < 4; ++r) {
          int mg = 16 * mt + g4 * 4 + r;
          int oxi = 16 * jj + ml - (g4 * 4 + r);   // jg - mg
          if ((unsigned)oxi < 21u) eb[oxi][p + 2 * mg] = acc[mt * 3 + jj][r] * sc;
        }
  }
  __syncthreads();
  if (cs == 1) {
#pragma unroll
    for (int mt = 0; mt < 4; ++mt)
#pragma unroll
      for (int jj = 0; jj < 3; ++jj)
#pragma unroll
        for (int r = 0; r < 4; ++r) {
          int mg = 16 * mt + g4 * 4 + r;
          int oxi = 16 * jj + ml - (g4 * 4 + r);
          if ((unsigned)oxi < 21u) eb[oxi][p + 2 * mg] += acc[mt * 3 + jj][r] * sc;
        }
  }
  __syncthreads();
  for (int i = tid; i < 672; i += 256) {
    int oxi = i >> 5, xq = i & 31;
    size_t o = (((size_t)(b * 441 + dyi * 21 + oxi)) * 96 + y) * 128 + xq * 4;
    f32x4 v = *reinterpret_cast<f32x4*>(&eb[oxi][xq * 4]);
    *reinterpret_cast<f32x4*>(out + o) = v;
  }
}

// ---------------- workspace-free f32 fallback (only if ws_size too small) ----
__global__ __launch_bounds__(256) void corr_fallback(const float* __restrict__ in1,
                                                     const float* __restrict__ in2,
                                                     float* __restrict__ out) {
  __shared__ float s1[64][129];
  __shared__ float s2[64][129];
  int bid = blockIdx.x;            // 16128 = 8*96*21
  int b = bid / 2016;
  int r0 = bid % 2016;
  int y = r0 / 21;
  int dyi = r0 % 21;
  int y2 = y + 2 * dyi - 20;
  int tid = threadIdx.x;
  bool rowvalid = (unsigned)y2 < 96u;

  float acc[11];
#pragma unroll
  for (int j = 0; j < 11; ++j) acc[j] = 0.f;

  if (rowvalid) {
    for (int cc = 0; cc < 4; ++cc) {
      int c0 = cc * 64;
      __syncthreads();
      for (int i = tid; i < 8192; i += 256) {
        int c = i >> 7, x = i & 127;
        s1[c][x] = in1[(((size_t)(b * 256 + c0 + c)) * 96 + y) * 128 + x];
        s2[c][x] = in2[(((size_t)(b * 256 + c0 + c)) * 96 + y2) * 128 + x];
      }
      __syncthreads();
#pragma unroll
      for (int j = 0; j < 11; ++j) {
        int idx = j * 256 + tid;
        if (idx < 2688) {
          int oxi = idx >> 7, x = idx & 127;
          int x2 = x + 2 * oxi - 20;
          if ((unsigned)x2 < 128u) {
            float a = 0.f;
            for (int c = 0; c < 64; ++c) a += s1[c][x] * s2[c][x2];
            acc[j] += a;
          }
        }
      }
    }
  }
#pragma unroll
  for (int j = 0; j < 11; ++j) {
    int idx = j * 256 + tid;
    if (idx < 2688) {
      int oxi = idx >> 7, x = idx & 127;
      out[(((size_t)(b * 441 + dyi * 21 + oxi)) * 96 + y) * 128 + x] = acc[j] * (1.0f / 256.0f);
    }
  }
}

extern "C" void kernel_launch(void* const* d_in, const int* in_sizes, int n_in,
                              void* d_out, int out_size, void* d_ws, size_t ws_size,
                              hipStream_t stream) {
  const float* in1 = (const float*)d_in[0];
  const float* in2 = (const float*)d_in[1];
  float* out = (float*)d_out;

  if (ws_size >= WS_NEEDED) {
    unsigned short* in1t = (unsigned short*)d_ws;
    unsigned short* in2t = (unsigned short*)((char*)d_ws + IN1T_BYTES);
    t1_kernel<<<3072, 256, 0, stream>>>(in1, in1t);
    t2_kernel<<<3072, 256, 0, stream>>>(in2, in2t);
    corr_kernel<<<16128, 256, 0, stream>>>(in1t, in2t, out);
  } else {
    corr_fallback<<<16128, 256, 0, stream>>>(in1, in2, out);
  }
}

// Round 4
// 492.823 us; speedup vs baseline: 1.2247x; 1.2247x over previous
//
#include <hip/hip_runtime.h>
#include <hip/hip_bf16.h>

// FlowNetC correlation on MI355X (gfx950).
// out[b, dyi*21+dxi, y, x] = (1/256) * sum_c in1[b,c,y,x] * in2pad[b,c, y+2dyi-20, x+2dxi-20]
//
// R3 design: block = (b,y); A row (in1) lives in REGISTERS (full K=256, loaded
// once); loop dyi=0..20, staging the B row (in2t[y2]) in 64-channel chunks,
// double-buffered with counted vmcnt(6) + raw barriers (no vmcnt(0) drains).
// Band GEMM via mfma_f32_16x16x32_bf16; scattered reg->global epilogue.

typedef short short8 __attribute__((ext_vector_type(8)));
typedef float f32x4 __attribute__((ext_vector_type(4)));

// in1t: [8][96][2][64][256] bf16 = 50331648 B  (plain layout)
// in2t: [8][96][2][96][256] bf16 = 75497472 B  (zero-padded, XOR-swizzled 16B c-blocks)
#define IN1T_BYTES 50331648ull
#define WS_NEEDED 125829120ull

__device__ __forceinline__ unsigned short f2bf(float f) {
  union { float f; unsigned int u; } v; v.f = f;
  unsigned int u = v.u;
  u += 0x7fffu + ((u >> 16) & 1u);   // round-to-nearest-even
  return (unsigned short)(u >> 16);
}

__device__ __forceinline__ void gload16(const unsigned short* g, unsigned short* l) {
  __builtin_amdgcn_global_load_lds((__attribute__((address_space(1))) unsigned int*)g,
                                   (__attribute__((address_space(3))) unsigned int*)l,
                                   16, 0, 0);
}

// ---------------- pre-pass: in1 -> in1t [b][y][p][m 64][c 256] (PLAIN) -------
__global__ __launch_bounds__(256) void t1_kernel(const float* __restrict__ in1,
                                                 unsigned short* __restrict__ in1t) {
  __shared__ float sm[64][129];
  int bid = blockIdx.x;            // 8*96*4
  int cchunk = bid & 3;
  int t = bid >> 2;
  int y = t % 96;
  int b = t / 96;
  int c0 = cchunk * 64;
  for (int i = threadIdx.x; i < 2048; i += 256) {
    int cl = i >> 5, xq = (i & 31) << 2;
    f32x4 v = *reinterpret_cast<const f32x4*>(
        in1 + (((size_t)(b * 256 + c0 + cl)) * 96 + y) * 128 + xq);
    sm[cl][xq] = v[0]; sm[cl][xq + 1] = v[1]; sm[cl][xq + 2] = v[2]; sm[cl][xq + 3] = v[3];
  }
  __syncthreads();
  size_t obase = ((size_t)(b * 96 + y)) * 32768;
  for (int u = threadIdx.x; u < 1024; u += 256) {
    int p = u >> 9, m = (u >> 3) & 63, cb = u & 7;
    int x = p + 2 * m;
    short8 w;
#pragma unroll
    for (int e = 0; e < 8; ++e) w[e] = (short)f2bf(sm[cb * 8 + e][x]);
    size_t o = obase + ((size_t)(p * 64 + m)) * 256 + c0 + (cb << 3);
    *reinterpret_cast<short8*>(in1t + o) = w;
  }
}

// ---------------- pre-pass: in2 -> in2t [b][y2][p][k 96][c 256] (swizzled) ---
__global__ __launch_bounds__(256) void t2_kernel(const float* __restrict__ in2,
                                                 unsigned short* __restrict__ in2t) {
  __shared__ float sm[64][129];
  int bid = blockIdx.x;            // 8*96*4
  int cchunk = bid & 3;
  int t = bid >> 2;
  int y2 = t % 96;
  int b = t / 96;
  int c0 = cchunk * 64;
  for (int i = threadIdx.x; i < 2048; i += 256) {
    int cl = i >> 5, xq = (i & 31) << 2;
    f32x4 v = *reinterpret_cast<const f32x4*>(
        in2 + (((size_t)(b * 256 + c0 + cl)) * 96 + y2) * 128 + xq);
    sm[cl][xq] = v[0]; sm[cl][xq + 1] = v[1]; sm[cl][xq + 2] = v[2]; sm[cl][xq + 3] = v[3];
  }
  __syncthreads();
  size_t obase = ((size_t)(b * 96 + y2)) * 49152;
  for (int u = threadIdx.x; u < 1536; u += 256) {
    int p = u / 768;
    int r = u % 768;
    int k = r >> 3, cb = r & 7;
    int x2 = p + 2 * k - 20;
    bool ok = (unsigned)x2 < 128u;
    short8 w;
#pragma unroll
    for (int e = 0; e < 8; ++e) w[e] = ok ? (short)f2bf(sm[cb * 8 + e][x2]) : (short)0;
    size_t o = obase + ((size_t)(p * 96 + k)) * 256 + c0 + ((cb ^ (k & 7)) << 3);
    *reinterpret_cast<short8*>(in2t + o) = w;
  }
}

// ---------------- correlation kernel ----------------
// block = (b, y), 256 threads = 4 waves = (parity p, m-pair sm2)
// LDS: B dbuf 2 x [192 rows(2p x 96k)][64c] bf16 = 48 KB -> 3 blocks/CU
__global__ __launch_bounds__(256, 3) void corr_kernel(const unsigned short* __restrict__ in1t,
                                                      const unsigned short* __restrict__ in2t,
                                                      float* __restrict__ out) {
  __shared__ unsigned short ldsB[2][192][64];

  int bid = blockIdx.x;                 // 768 = 8*96
  int wg = (bid & 7) * 96 + (bid >> 3); // bijective XCD swizzle (768 % 8 == 0)
  int b = wg / 96, y = wg % 96;
  int tid = threadIdx.x, lane = tid & 63, wid = tid >> 6;
  int p = wid & 1, sm2 = wid >> 1;
  int ml = lane & 15, g4 = lane >> 4, q = lane & 7, i8 = lane >> 3;

  // ---- A fragments: full K=256 in registers, loaded once ----
  short8 af[2][8];
  {
    const unsigned short* Ap = in1t + ((size_t)(b * 96 + y)) * 32768 + (size_t)p * 16384;
#pragma unroll
    for (int l = 0; l < 2; ++l) {
      const unsigned short* Ar = Ap + (size_t)((sm2 * 2 + l) * 16 + ml) * 256 + g4 * 8;
#pragma unroll
      for (int ks = 0; ks < 8; ++ks)
        af[l][ks] = *reinterpret_cast<const short8*>(Ar + ks * 32);
    }
  }

  size_t b96y2base = (size_t)(b * 96);
  auto stage = [&](int y2c, int cc, int buf) {
    const unsigned short* g = in2t + (b96y2base + y2c) * 49152 + cc * 64 + q * 8;
    unsigned short* l0 = &ldsB[buf][0][0] + lane * 8;
#pragma unroll
    for (int j = 0; j < 6; ++j) {
      int t = wid * 6 + j;               // 0..23, rows 8t..8t+7
      gload16(g + (size_t)(t * 8 + i8) * 256, l0 + t * 512);
    }
  };
  auto y2clamp = [&](int d) { int v = y + 2 * d - 20; return ((unsigned)v < 96u) ? v : 0; };

  stage(y2clamp(0), 0, 0);

  f32x4 acc[2][3];
  const float sc = 1.0f / 256.0f;

  for (int dyi = 0; dyi < 21; ++dyi) {
    bool valid = ((unsigned)(y + 2 * dyi - 20) < 96u);   // block-uniform
#pragma unroll
    for (int cc = 0; cc < 4; ++cc) {
      if (cc == 0) {
#pragma unroll
        for (int l = 0; l < 2; ++l)
#pragma unroll
          for (int jj = 0; jj < 3; ++jj) acc[l][jj] = (f32x4){0.f, 0.f, 0.f, 0.f};
      }
      // prefetch next chunk (1 ahead; dummy-safe past the end)
      { int ndyi = dyi + (cc == 3 ? 1 : 0);
        stage(y2clamp(ndyi), (cc + 1) & 3, (cc + 1) & 1); }
      asm volatile("s_waitcnt vmcnt(6)" ::: "memory");   // stage(n) done; n+1 in flight
      __builtin_amdgcn_s_barrier();
      if (valid) {
#pragma unroll
        for (int ks = 0; ks < 2; ++ks) {
          short8 bf[4];
#pragma unroll
          for (int t = 0; t < 4; ++t) {
            int row = p * 96 + (sm2 * 2 + t) * 16 + ml;
            bf[t] = *reinterpret_cast<const short8*>(
                &ldsB[cc & 1][0][0] + row * 64 + (((ks * 4 + g4) ^ q) << 3));
          }
#pragma unroll
          for (int l = 0; l < 2; ++l)
#pragma unroll
            for (int jj = 0; jj < 3; ++jj)
              acc[l][jj] = __builtin_amdgcn_mfma_f32_16x16x32_bf16(
                  af[l][cc * 2 + ks], bf[l + jj], acc[l][jj], 0, 0, 0);
        }
      }
      asm volatile("s_waitcnt lgkmcnt(0)" ::: "memory"); // ds_reads done before buf reuse
      __builtin_amdgcn_sched_barrier(0);
      __builtin_amdgcn_s_barrier();
      if (cc == 3) {
        if (valid) {
#pragma unroll
          for (int l = 0; l < 2; ++l) {
            int x0 = p + 2 * ((sm2 * 2 + l) * 16 + g4 * 4);
#pragma unroll
            for (int jj = 0; jj < 3; ++jj)
#pragma unroll
              for (int r = 0; r < 4; ++r) {
                int oxi = 16 * jj + ml - g4 * 4 - r;
                if ((unsigned)oxi < 21u)
                  out[(((size_t)(b * 441 + dyi * 21 + oxi)) * 96 + y) * 128 + x0 + 2 * r] =
                      acc[l][jj][r] * sc;
              }
          }
        } else {
          f32x4 z = {0.f, 0.f, 0.f, 0.f};
          for (int i = tid; i < 672; i += 256) {
            int oxi = i >> 5, xq = i & 31;
            *reinterpret_cast<f32x4*>(
                out + (((size_t)(b * 441 + dyi * 21 + oxi)) * 96 + y) * 128 + xq * 4) = z;
          }
        }
      }
    }
  }
}

// ---------------- workspace-free f32 fallback (only if ws_size too small) ----
__global__ __launch_bounds__(256) void corr_fallback(const float* __restrict__ in1,
                                                     const float* __restrict__ in2,
                                                     float* __restrict__ out) {
  __shared__ float s1[64][129];
  __shared__ float s2[64][129];
  int bid = blockIdx.x;            // 16128 = 8*96*21
  int b = bid / 2016;
  int r0 = bid % 2016;
  int y = r0 / 21;
  int dyi = r0 % 21;
  int y2 = y + 2 * dyi - 20;
  int tid = threadIdx.x;
  bool rowvalid = (unsigned)y2 < 96u;

  float acc[11];
#pragma unroll
  for (int j = 0; j < 11; ++j) acc[j] = 0.f;

  if (rowvalid) {
    for (int cc = 0; cc < 4; ++cc) {
      int c0 = cc * 64;
      __syncthreads();
      for (int i = tid; i < 8192; i += 256) {
        int c = i >> 7, x = i & 127;
        s1[c][x] = in1[(((size_t)(b * 256 + c0 + c)) * 96 + y) * 128 + x];
        s2[c][x] = in2[(((size_t)(b * 256 + c0 + c)) * 96 + y2) * 128 + x];
      }
      __syncthreads();
#pragma unroll
      for (int j = 0; j < 11; ++j) {
        int idx = j * 256 + tid;
        if (idx < 2688) {
          int oxi = idx >> 7, x = idx & 127;
          int x2 = x + 2 * oxi - 20;
          if ((unsigned)x2 < 128u) {
            float a = 0.f;
            for (int c = 0; c < 64; ++c) a += s1[c][x] * s2[c][x2];
            acc[j] += a;
          }
        }
      }
    }
  }
#pragma unroll
  for (int j = 0; j < 11; ++j) {
    int idx = j * 256 + tid;
    if (idx < 2688) {
      int oxi = idx >> 7, x = idx & 127;
      out[(((size_t)(b * 441 + dyi * 21 + oxi)) * 96 + y) * 128 + x] = acc[j] * (1.0f / 256.0f);
    }
  }
}

extern "C" void kernel_launch(void* const* d_in, const int* in_sizes, int n_in,
                              void* d_out, int out_size, void* d_ws, size_t ws_size,
                              hipStream_t stream) {
  const float* in1 = (const float*)d_in[0];
  const float* in2 = (const float*)d_in[1];
  float* out = (float*)d_out;

  if (ws_size >= WS_NEEDED) {
    unsigned short* in1t = (unsigned short*)d_ws;
    unsigned short* in2t = (unsigned short*)((char*)d_ws + IN1T_BYTES);
    t1_kernel<<<3072, 256, 0, stream>>>(in1, in1t);
    t2_kernel<<<3072, 256, 0, stream>>>(in2, in2t);
    corr_kernel<<<768, 256, 0, stream>>>(in1t, in2t, out);
  } else {
    corr_fallback<<<16128, 256, 0, stream>>>(in1, in2, out);
  }
}